// Round 1
// baseline (742.096 us; speedup 1.0000x reference)
//
#include <hip/hip_runtime.h>

#define NB 64
#define NT 512
#define NH 1024
#define NC 8
#define NK 3
#define BT (NB*NT)             // 32768
#define LOGITS_N (NK*BT*NC)    // 786432

// ---------------- init: zero loss, pre-load bias into logits ----------------
__global__ __launch_bounds__(256) void init_out(const float* __restrict__ bias,
                                                float* __restrict__ out) {
  int i = blockIdx.x * 256 + threadIdx.x;
  if (i < LOGITS_N) {
    int k = i >> 18;          // 64*512*8 = 2^18
    int c = i & 7;
    out[1 + i] = bias[k * 8 + c];
  }
  if (i == 0) out[0] = 0.0f;
}

// ---------------- GEMM: logits += enc @ W^T (partial over H, atomics) -------
// grid 256 = 32 rowblocks x 8 h-splits; block 256 threads; 4 rows/thread.
__global__ __launch_bounds__(256) void gemm_partial(const float* __restrict__ enc,
                                                    const float* __restrict__ W,
                                                    float* __restrict__ logits) {
  __shared__ float sW[24 * 128];
  const int tid = threadIdx.x;
  const int bid = blockIdx.x;
  const int hs = bid & 7;     // which 128-wide H chunk
  const int rb = bid >> 3;    // row block 0..31 (1024 rows each)

  // stage W slice: W[j][hs*128 .. hs*128+128), j = k*8+c in 0..23
#pragma unroll
  for (int r = 0; r < 3; ++r) {
    int f = tid + 256 * r;        // float4 index 0..767
    int d = f * 4;                // flat float index
    int j = d >> 7;
    int hi = d & 127;
    *(float4*)&sW[d] = *(const float4*)&W[j * 1024 + hs * 128 + hi];
  }
  __syncthreads();

  float acc[4][24];
#pragma unroll
  for (int ri = 0; ri < 4; ++ri)
#pragma unroll
    for (int j = 0; j < 24; ++j) acc[ri][j] = 0.0f;

  const int rowbase = rb * 1024 + tid * 4;
  const float* ebase = enc + (size_t)rowbase * 1024 + hs * 128;

  for (int hi = 0; hi < 128; hi += 4) {
    float4 e0 = *(const float4*)(ebase + 0 * 1024 + hi);
    float4 e1 = *(const float4*)(ebase + 1 * 1024 + hi);
    float4 e2 = *(const float4*)(ebase + 2 * 1024 + hi);
    float4 e3 = *(const float4*)(ebase + 3 * 1024 + hi);
#pragma unroll
    for (int j = 0; j < 24; ++j) {
      float4 w = *(float4*)&sW[j * 128 + hi];
      acc[0][j] += e0.x * w.x + e0.y * w.y + e0.z * w.z + e0.w * w.w;
      acc[1][j] += e1.x * w.x + e1.y * w.y + e1.z * w.z + e1.w * w.w;
      acc[2][j] += e2.x * w.x + e2.y * w.y + e2.z * w.z + e2.w * w.w;
      acc[3][j] += e3.x * w.x + e3.y * w.y + e3.z * w.z + e3.w * w.w;
    }
  }

#pragma unroll
  for (int ri = 0; ri < 4; ++ri) {
    int row = rowbase + ri;
#pragma unroll
    for (int j = 0; j < 24; ++j) {
      int k = j >> 3, c = j & 7;
      atomicAdd(&logits[((size_t)k * BT + row) * 8 + c], acc[ri][j]);
    }
  }
}

// ---------------- fused CRF: forward logZ + viterbi + backtrace + loss ------
// grid 24 blocks x 64 threads; each wave handles 8 sequences (8 lanes/seq).
// lane = g*8 + c : g = sequence-in-block, c = state.
__global__ __launch_bounds__(64) void crf_kernel(const float* __restrict__ out_logits,
                                                 const int* __restrict__ labels,
                                                 const float* __restrict__ startT,
                                                 const float* __restrict__ endT,
                                                 const float* __restrict__ trans,
                                                 float* __restrict__ d_out) {
  __shared__ float sA[64];
  __shared__ float sV[64];
  __shared__ __align__(8) unsigned char sBP[8][4104];  // [g][t*8+c], padded stride

  const int lane = threadIdx.x;
  const int g = lane >> 3, c = lane & 7;
  const int seq = blockIdx.x * 8 + g;           // 0..191
  const int k = seq >> 6, b = seq & 63;

  const float* em = out_logits + (size_t)seq * (NT * NC);
  const float* startk = startT + k * 8;
  const float* endk = endT + k * 8;
  const float* trk = trans + k * 64;

  float Tcol[8], Mcol[8];
#pragma unroll
  for (int p = 0; p < 8; ++p) {
    Tcol[p] = trk[p * 8 + c];       // trans[prev=p][cur=c]
    Mcol[p] = __expf(Tcol[p]);
  }

  float e0 = em[c];                          // em[t=0][c]
  float alpha = __expf(startk[c] + e0);      // linear-domain forward var
  float v = startk[c] + e0;                  // viterbi score (log domain)
  float logZacc = 0.0f;

  float ecur[8];
#pragma unroll
  for (int i = 0; i < 8; ++i) ecur[i] = em[i * 8 + c];

  unsigned char* bpg = sBP[g];

  for (int t0 = 0; t0 < 512; t0 += 8) {
    float enext[8];
    if (t0 + 8 < 512) {
#pragma unroll
      for (int i = 0; i < 8; ++i) enext[i] = em[(t0 + 8 + i) * 8 + c];
    } else {
#pragma unroll
      for (int i = 0; i < 8; ++i) enext[i] = 0.0f;
    }
    float ex[8];
#pragma unroll
    for (int i = 0; i < 8; ++i) ex[i] = __expf(ecur[i]);

#pragma unroll
    for (int j = 0; j < 8; ++j) {
      int t = t0 + j;
      if (t0 == 0 && j == 0) continue;   // t=0 handled by init
      // ---- forward (linear domain) ----
      sA[lane] = alpha;
      float4 a0 = *(float4*)&sA[g * 8];
      float4 a1 = *(float4*)&sA[g * 8 + 4];
      float s = a0.x * Mcol[0] + a0.y * Mcol[1] + a0.z * Mcol[2] + a0.w * Mcol[3]
              + a1.x * Mcol[4] + a1.y * Mcol[5] + a1.z * Mcol[6] + a1.w * Mcol[7];
      alpha = s * ex[j];
      // ---- viterbi ----
      sV[lane] = v;
      float4 v0 = *(float4*)&sV[g * 8];
      float4 v1 = *(float4*)&sV[g * 8 + 4];
      float vv[8] = {v0.x, v0.y, v0.z, v0.w, v1.x, v1.y, v1.z, v1.w};
      float best = vv[0] + Tcol[0];
      int arg = 0;
#pragma unroll
      for (int p = 1; p < 8; ++p) {
        float cand = vv[p] + Tcol[p];
        if (cand > best) { best = cand; arg = p; }   // first-max tie-break
      }
      v = best + ecur[j];
      bpg[t * 8 + c] = (unsigned char)arg;
    }

    // normalize alpha across the 8 states of this sequence
    float sum = alpha;
    sum += __shfl_xor(sum, 1);
    sum += __shfl_xor(sum, 2);
    sum += __shfl_xor(sum, 4);
    logZacc += __logf(sum);
    alpha *= 1.0f / sum;

#pragma unroll
    for (int i = 0; i < 8; ++i) ecur[i] = enext[i];
  }

  // logZ = logZacc + log( sum_c alpha[c] * exp(end[c]) )
  float se = alpha * __expf(endk[c]);
  se += __shfl_xor(se, 1);
  se += __shfl_xor(se, 2);
  se += __shfl_xor(se, 4);
  float logZ = logZacc + __logf(se);

  // viterbi terminal argmax (first max on ties)
  float lv = v + endk[c];
  int li = c;
#pragma unroll
  for (int m = 1; m < 8; m <<= 1) {
    float ov = __shfl_xor(lv, m);
    int oi = __shfl_xor(li, m);
    if (ov > lv || (ov == lv && oi < li)) { lv = ov; li = oi; }
  }

  // gold-path numerator (8 lanes per sequence split t)
  const int* lab = labels + b * (NK * NT) + k * NT;
  float nsum = 0.0f;
  for (int i = 0; i < 64; ++i) {
    int t = c + i * 8;
    int tg = lab[t];
    nsum += em[t * 8 + tg];
    if (t < 511) nsum += trk[tg * 8 + lab[t + 1]];
  }
  nsum += __shfl_xor(nsum, 1);
  nsum += __shfl_xor(nsum, 2);
  nsum += __shfl_xor(nsum, 4);

  float* predf = d_out + 1 + LOGITS_N + (size_t)seq * NT;
  if (c == 0) {
    float num = nsum + startk[lab[0]] + endk[lab[511]];
    atomicAdd(d_out, logZ - num);

    // backtrace: row loads are address-independent of the tag chain
    predf[511] = (float)li;
    int tag = li;
    int t = 511;
    while (t >= 1) {
      int n = (t >= 8) ? 8 : t;
      unsigned long long rows[8];
#pragma unroll
      for (int i = 0; i < 8; ++i)
        if (i < n) rows[i] = *(const unsigned long long*)&bpg[(t - i) * 8];
#pragma unroll
      for (int i = 0; i < 8; ++i)
        if (i < n) {
          tag = (int)((rows[i] >> (tag * 8)) & 7ULL);
          predf[t - i - 1] = (float)tag;
        }
      t -= n;
    }
  }
}

extern "C" void kernel_launch(void* const* d_in, const int* in_sizes, int n_in,
                              void* d_out, int out_size, void* d_ws, size_t ws_size,
                              hipStream_t stream) {
  const float* enc    = (const float*)d_in[0];
  const int*   labels = (const int*)  d_in[1];
  const float* W      = (const float*)d_in[2];
  const float* bias   = (const float*)d_in[3];
  const float* startT = (const float*)d_in[4];
  const float* endT   = (const float*)d_in[5];
  const float* trans  = (const float*)d_in[6];
  float* out = (float*)d_out;

  init_out<<<dim3(3072), dim3(256), 0, stream>>>(bias, out);
  gemm_partial<<<dim3(256), dim3(256), 0, stream>>>(enc, W, out + 1);
  crf_kernel<<<dim3(24), dim3(64), 0, stream>>>(out + 1, labels, startT, endT, trans, out);
}

// Round 2
// 355.421 us; speedup vs baseline: 2.0879x; 2.0879x over previous
//
#include <hip/hip_runtime.h>

#define NB 64
#define NT 512
#define NH 1024
#define NC 8
#define NK 3
#define BT (NB*NT)             // 32768
#define LOGITS_N (NK*BT*NC)    // 786432

// ---------------- init: zero loss, transpose W -> Wt[h][24] in d_ws --------
__global__ __launch_bounds__(256) void init_kernel(const float* __restrict__ W,
                                                   float* __restrict__ Wt,
                                                   float* __restrict__ out) {
  int i = blockIdx.x * 256 + threadIdx.x;
  if (i < 24 * NH) {
    int h = i / 24, j = i - h * 24;
    int k = j >> 3, c = j & 7;
    Wt[i] = W[k * NC * NH + c * NH + h];   // Wt[h*24 + j] = W[k][c][h]
  }
  if (i == 0) out[0] = 0.0f;
}

// ---------------- proj: logits[k][row][c] = enc[row] . W[k][c] + b ----------
// grid 512 x 64 threads; 1 row per thread; enc staged via LDS coalesced;
// Wt read at wave-uniform addresses (scalar loads -> SGPR FMA operands).
__global__ __launch_bounds__(64) void proj_kernel(const float* __restrict__ enc,
                                                  const float* __restrict__ Wt,
                                                  const float* __restrict__ bias,
                                                  float* __restrict__ out) {
  __shared__ float sE[64 * 33];           // stride 33: (i+h)%32 -> 2-way = free
  const int tid = threadIdx.x;
  const int row0 = blockIdx.x * 64;

  float acc[24];
#pragma unroll
  for (int j = 0; j < 24; ++j) acc[j] = 0.0f;

  const float* eb = enc + (size_t)row0 * 1024;
  float4 pf[8];
  // preload chunk 0: float4 slot f = tid + 64*s; row r=f>>3; col=(f&7)*4
#pragma unroll
  for (int s = 0; s < 8; ++s) {
    int f = tid + 64 * s;
    pf[s] = *(const float4*)(eb + (f >> 3) * 1024 + (f & 7) * 4);
  }

  for (int ch = 0; ch < 32; ++ch) {
    __syncthreads();
#pragma unroll
    for (int s = 0; s < 8; ++s) {
      int f = tid + 64 * s;
      int base = (f >> 3) * 33 + (f & 7) * 4;
      sE[base + 0] = pf[s].x; sE[base + 1] = pf[s].y;
      sE[base + 2] = pf[s].z; sE[base + 3] = pf[s].w;
    }
    __syncthreads();
    if (ch < 31) {
      int hb = (ch + 1) * 32;
#pragma unroll
      for (int s = 0; s < 8; ++s) {
        int f = tid + 64 * s;
        pf[s] = *(const float4*)(eb + (f >> 3) * 1024 + hb + (f & 7) * 4);
      }
    }
    const float* wrow = Wt + ch * 32 * 24;   // wave-uniform
#pragma unroll 8
    for (int h = 0; h < 32; ++h) {
      float e = sE[tid * 33 + h];
#pragma unroll
      for (int j = 0; j < 24; ++j)
        acc[j] = fmaf(e, wrow[h * 24 + j], acc[j]);
    }
  }

  int row = row0 + tid;
#pragma unroll
  for (int k = 0; k < 3; ++k) {
    size_t base = ((size_t)k * BT + row) * 8;
#pragma unroll
    for (int c = 0; c < 8; ++c)
      out[1 + base + c] = acc[k * 8 + c] + bias[k * 8 + c];   // out+1: no 16B align
  }
}

// ---------------- CRF: blocks 0..23 forward+loss, 24..47 viterbi+preds -----
// 64 threads = 1 wave; lane = g*8+c (8 sequences x 8 states per wave).
__global__ __launch_bounds__(64) void crf_kernel(const float* __restrict__ logits,
                                                 const int* __restrict__ labels,
                                                 const float* __restrict__ startT,
                                                 const float* __restrict__ endT,
                                                 const float* __restrict__ trans,
                                                 float* __restrict__ d_out) {
  __shared__ __align__(8) unsigned char sBP[8][4104];  // byte bp rows, padded stride
  __shared__ unsigned char sTagsB[4096];

  const int lane = threadIdx.x;
  const int g = lane >> 3, c = lane & 7, gb = lane & 56;
  const int role = (blockIdx.x < 24) ? 0 : 1;
  const int sb = role ? (blockIdx.x - 24) : blockIdx.x;
  const int seq = sb * 8 + g;               // 0..191
  const int k = seq >> 6, b = seq & 63;

  const float* em = logits + (size_t)seq * (NT * NC);
  const float* trk = trans + k * 64;

  float Tcol[8], Mcol[8];
#pragma unroll
  for (int p = 0; p < 8; ++p) {
    Tcol[p] = trk[p * 8 + c];
    Mcol[p] = __expf(Tcol[p]);
  }
  const float startc = startT[k * 8 + c];
  const float endc = endT[k * 8 + c];
  const float e00 = em[c];

  float ecur[8];
#pragma unroll
  for (int i = 0; i < 8; ++i) ecur[i] = em[i * 8 + c];

  if (role == 0) {
    // ---------------- forward (linear domain, normalized every 8) ----------
    float alpha = __expf(startc + e00);
    float logZacc = 0.0f;
    for (int t0 = 0; t0 < 512; t0 += 8) {
      float enext[8];
      if (t0 + 8 < 512) {
#pragma unroll
        for (int i = 0; i < 8; ++i) enext[i] = em[(t0 + 8 + i) * 8 + c];
      } else {
#pragma unroll
        for (int i = 0; i < 8; ++i) enext[i] = 0.0f;
      }
      float ex[8];
#pragma unroll
      for (int i = 0; i < 8; ++i) ex[i] = __expf(ecur[i]);
#pragma unroll
      for (int j = 0; j < 8; ++j) {
        if (t0 == 0 && j == 0) continue;
        float ap[8];
#pragma unroll
        for (int p = 0; p < 8; ++p) ap[p] = __shfl(alpha, gb + p, 64);
        float s = ((ap[0] * Mcol[0] + ap[1] * Mcol[1]) + (ap[2] * Mcol[2] + ap[3] * Mcol[3]))
                + ((ap[4] * Mcol[4] + ap[5] * Mcol[5]) + (ap[6] * Mcol[6] + ap[7] * Mcol[7]));
        alpha = s * ex[j];
      }
      float sum = alpha;
      sum += __shfl_xor(sum, 1); sum += __shfl_xor(sum, 2); sum += __shfl_xor(sum, 4);
      logZacc += __logf(sum);
      alpha *= (1.0f / sum);
#pragma unroll
      for (int i = 0; i < 8; ++i) ecur[i] = enext[i];
    }
    float se = alpha * __expf(endc);
    se += __shfl_xor(se, 1); se += __shfl_xor(se, 2); se += __shfl_xor(se, 4);
    float logZ = logZacc + __logf(se);

    // gold-path numerator
    const int* lab = labels + b * (NK * NT) + k * NT;
    float nsum = 0.0f;
    for (int i = 0; i < 64; ++i) {
      int t = c + i * 8;
      int tg = lab[t];
      nsum += em[t * 8 + tg];
      if (t < 511) nsum += trk[tg * 8 + lab[t + 1]];
    }
    nsum += __shfl_xor(nsum, 1); nsum += __shfl_xor(nsum, 2); nsum += __shfl_xor(nsum, 4);
    if (c == 0) {
      float num = nsum + startT[k * 8 + lab[0]] + endT[k * 8 + lab[511]];
      atomicAdd(d_out, logZ - num);
    }
  } else {
    // ---------------- viterbi ----------------
    float v = startc + e00;
    unsigned char* bpg = sBP[g];
    for (int t0 = 0; t0 < 512; t0 += 8) {
      float enext[8];
      if (t0 + 8 < 512) {
#pragma unroll
        for (int i = 0; i < 8; ++i) enext[i] = em[(t0 + 8 + i) * 8 + c];
      } else {
#pragma unroll
        for (int i = 0; i < 8; ++i) enext[i] = 0.0f;
      }
#pragma unroll
      for (int j = 0; j < 8; ++j) {
        if (t0 == 0 && j == 0) continue;
        int t = t0 + j;
        float vp[8];
#pragma unroll
        for (int p = 0; p < 8; ++p) vp[p] = __shfl(v, gb + p, 64) + Tcol[p];
        // first-max argmax tree (left operand always has smaller indices)
        float v01 = vp[0]; int i01 = 0; if (vp[1] > v01) { v01 = vp[1]; i01 = 1; }
        float v23 = vp[2]; int i23 = 2; if (vp[3] > v23) { v23 = vp[3]; i23 = 3; }
        float v45 = vp[4]; int i45 = 4; if (vp[5] > v45) { v45 = vp[5]; i45 = 5; }
        float v67 = vp[6]; int i67 = 6; if (vp[7] > v67) { v67 = vp[7]; i67 = 7; }
        float v03 = v01; int i03 = i01; if (v23 > v03) { v03 = v23; i03 = i23; }
        float v47 = v45; int i47 = i45; if (v67 > v47) { v47 = v67; i47 = i67; }
        float best = v03; int arg = i03; if (v47 > best) { best = v47; arg = i47; }
        v = best + ecur[j];
        bpg[t * 8 + c] = (unsigned char)arg;
      }
#pragma unroll
      for (int i = 0; i < 8; ++i) ecur[i] = enext[i];
    }
    // terminal argmax (first max on ties) across the 8 group lanes
    float lv = v + endc;
    int li = c;
#pragma unroll
    for (int m = 1; m < 8; m <<= 1) {
      float ov = __shfl_xor(lv, m);
      int oi = __shfl_xor(li, m);
      if (ov > lv || (ov == lv && oi < li)) { lv = ov; li = oi; }
    }
    __syncthreads();
    if (c == 0) {
      int tag = li;
      sTagsB[g * 512 + 511] = (unsigned char)tag;
      int t = 511;
      while (t >= 1) {
        int n = (t >= 8) ? 8 : t;
        unsigned long long rows[8];
#pragma unroll
        for (int i = 0; i < 8; ++i)
          if (i < n) rows[i] = *(const unsigned long long*)&bpg[(t - i) * 8];
#pragma unroll
        for (int i = 0; i < 8; ++i)
          if (i < n) {
            tag = (int)((rows[i] >> (tag * 8)) & 7ULL);
            sTagsB[g * 512 + t - i - 1] = (unsigned char)tag;
          }
        t -= n;
      }
    }
    __syncthreads();
    // cooperative coalesced store of this block's 8 sequences of preds
    float* outp = d_out + 1 + LOGITS_N + (size_t)sb * 4096;
    for (int u = 0; u < 64; ++u) {
      int idx = u * 64 + lane;
      outp[idx] = (float)sTagsB[idx];
    }
  }
}

extern "C" void kernel_launch(void* const* d_in, const int* in_sizes, int n_in,
                              void* d_out, int out_size, void* d_ws, size_t ws_size,
                              hipStream_t stream) {
  const float* enc    = (const float*)d_in[0];
  const int*   labels = (const int*)  d_in[1];
  const float* W      = (const float*)d_in[2];
  const float* bias   = (const float*)d_in[3];
  const float* startT = (const float*)d_in[4];
  const float* endT   = (const float*)d_in[5];
  const float* trans  = (const float*)d_in[6];
  float* out = (float*)d_out;
  float* Wt  = (float*)d_ws;   // 24*1024 floats = 96 KB scratch

  init_kernel<<<dim3(96), dim3(256), 0, stream>>>(W, Wt, out);
  proj_kernel<<<dim3(512), dim3(64), 0, stream>>>(enc, Wt, bias, out);
  crf_kernel<<<dim3(48), dim3(64), 0, stream>>>(out + 1, labels, startT, endT, trans, out);
}